// Round 3
// baseline (30.904 us; speedup 1.0000x reference)
//
#include <hip/hip_runtime.h>
#include <math.h>

// Problem constants: B=4, R=4096, S=48, C=32
#define NRAYS   (4 * 4096)   // 16384
#define S_SAMP  48
#define C_CH    32
#define SM1     (S_SAMP - 1) // 47

// Output flat layout (floats):
//   composite_rgb   [NRAYS * C_CH]  at 0
//   composite_depth [NRAYS]         at NRAYS*C_CH
//   weights         [NRAYS * SM1]
//   weight_total    [NRAYS]
#define OFF_RGB   0
#define OFF_DEP   (NRAYS * C_CH)
#define OFF_W     (OFF_DEP + NRAYS)
#define OFF_WT    (OFF_W + NRAYS * SM1)

// Single fused kernel: 16 lanes per ray, each lane owns a float2 channel pair.
// All 16 lanes redundantly run the serial scan (cheap with HW transcendentals:
// ~25 VALU instr/iter vs ~300 for the libcall softplus that sank round 1);
// color loads don't depend on the scan chain, so the compiler pipelines them
// ahead while the alpha/T chain executes.
__global__ __launch_bounds__(256) void fused_kernel(
    const float* __restrict__ colors,     // [NRAYS, S, C]
    const float* __restrict__ densities,  // [NRAYS, S]
    const float* __restrict__ depths,     // [NRAYS, S]
    float* __restrict__ out)
{
    const int tid = blockIdx.x * 256 + threadIdx.x;
    const int ray = tid >> 4;        // 16 threads per ray
    const int cq  = tid & 15;        // channel pair: channels 2*cq, 2*cq+1

    const float2* __restrict__ col2 =
        reinterpret_cast<const float2*>(colors) + (size_t)ray * S_SAMP * (C_CH / 2) + cq;
    const float* __restrict__ den = densities + (size_t)ray * S_SAMP;
    const float* __restrict__ dep = depths    + (size_t)ray * S_SAMP;
    float* __restrict__ w_out = out + OFF_W + (size_t)ray * SM1;

    // previous-sample registers (each HBM element read exactly once)
    float2 cp = col2[0];
    float  dp = den[0];
    float  zp = dep[0];

    float T = 1.0f;             // exclusive transmittance
    float wt = 0.0f;            // weight_total
    float dacc = 0.0f;          // sum w * depth_mid
    float ax = 0.0f, ay = 0.0f; // sum w * (c_prev + c)  (the *0.5*2 cancels)

    #pragma unroll 8
    for (int s = 1; s < S_SAMP; ++s) {
        const float2 c = col2[(size_t)s * (C_CH / 2)];
        const float  d = den[s];
        const float  z = dep[s];

        const float delta = z - zp;
        const float dmid  = 0.5f * (d + dp) - 1.0f;
        // fast stable softplus: max(x,0) + log(1 + exp(-|x|))
        const float e     = __expf(-fabsf(dmid));
        const float sp    = fmaxf(dmid, 0.0f) + __logf(1.0f + e);
        const float alpha = 1.0f - __expf(-sp * delta);
        const float w     = alpha * T;
        T *= (1.0f - alpha + 1e-10f);

        ax   += w * (c.x + cp.x);
        ay   += w * (c.y + cp.y);
        wt   += w;
        dacc += w * 0.5f * (z + zp);

        if (cq == 0) w_out[s - 1] = w;

        cp = c; dp = d; zp = z;
    }

    // composite_rgb = 2*sum(w*colors_mid) - 1 = ax - 1
    float* __restrict__ rgb = out + OFF_RGB + (size_t)ray * C_CH + 2 * cq;
    rgb[0] = ax - 1.0f;
    rgb[1] = ay - 1.0f;

    if (cq == 0) {
        out[OFF_DEP + ray] = dacc / (wt + 0.001f);
        out[OFF_WT  + ray] = wt;
    }
}

extern "C" void kernel_launch(void* const* d_in, const int* in_sizes, int n_in,
                              void* d_out, int out_size, void* d_ws, size_t ws_size,
                              hipStream_t stream) {
    const float* colors    = (const float*)d_in[0];
    const float* densities = (const float*)d_in[1];
    const float* depths    = (const float*)d_in[2];
    float* out = (float*)d_out;

    const int total_threads = NRAYS * 16;       // 262144
    fused_kernel<<<total_threads / 256, 256, 0, stream>>>(colors, densities, depths, out);
}

// Round 4
// 21.639 us; speedup vs baseline: 1.4281x; 1.4281x over previous
//
#include <hip/hip_runtime.h>
#include <math.h>

// Problem constants: B=4, R=4096, S=48, C=32
#define NRAYS   (4 * 4096)   // 16384
#define S_SAMP  48
#define C_CH    32
#define SM1     (S_SAMP - 1) // 47 midpoints

// Output flat layout (floats):
#define OFF_RGB   0
#define OFF_DEP   (NRAYS * C_CH)
#define OFF_W     (OFF_DEP + NRAYS)
#define OFF_WT    (OFF_W + NRAYS * SM1)

__device__ __forceinline__ float alpha_of(float da, float db, float za, float zb) {
    const float dmid = 0.5f * (da + db) - 1.0f;
    // fast stable softplus: max(x,0) + log(1 + exp(-|x|))
    const float e  = __expf(-fabsf(dmid));
    const float sp = fmaxf(dmid, 0.0f) + __logf(1.0f + e);
    return 1.0f - __expf(-sp * (zb - za));
}

// One 16-lane group per ray.
// Phase 1 (sample-parallel): lane l owns midpoints 3l..3l+2; alphas computed
//   independently; exclusive transmittance via 4-step shfl_up prefix product.
// Phase 2 (channel-parallel): lane l owns channel pair l; weights broadcast
//   from their owner lane via compile-time-indexed shfl.
__global__ __launch_bounds__(256) void fused2_kernel(
    const float* __restrict__ colors,     // [NRAYS, S, C]
    const float* __restrict__ densities,  // [NRAYS, S]
    const float* __restrict__ depths,     // [NRAYS, S]
    float* __restrict__ out)
{
    const int tid = blockIdx.x * 256 + threadIdx.x;
    const int ray = tid >> 4;
    const int l   = tid & 15;

    const float* __restrict__ den = densities + (size_t)ray * S_SAMP;
    const float* __restrict__ dep = depths    + (size_t)ray * S_SAMP;

    // ---- Phase 1: weights via lane-parallel scan -------------------------
    const int m0 = 3 * l;                 // first midpoint owned by this lane
    const float d0 = den[m0], d1 = den[m0 + 1], d2 = den[m0 + 2];
    const float z0 = dep[m0], z1 = dep[m0 + 1], z2 = dep[m0 + 2];
    float d3 = 0.0f, z3 = 0.0f;
    if (l < 15) { d3 = den[m0 + 3]; z3 = dep[m0 + 3]; }  // lane15: m=47 invalid

    const float a0 = alpha_of(d0, d1, z0, z1);
    const float a1 = alpha_of(d1, d2, z1, z2);
    const float a2 = (l < 15) ? alpha_of(d2, d3, z2, z3) : 0.0f;

    const float q0 = 1.0f - a0 + 1e-10f;
    const float q1 = 1.0f - a1 + 1e-10f;
    const float q2 = 1.0f - a2 + 1e-10f;

    // inclusive prefix product of per-lane products across the 16-lane group
    float scan = q0 * q1 * q2;
    #pragma unroll
    for (int off = 1; off < 16; off <<= 1) {
        const float t = __shfl_up(scan, off, 16);
        if (l >= off) scan *= t;
    }
    // exclusive
    float excl = __shfl_up(scan, 1, 16);
    if (l == 0) excl = 1.0f;

    const float T0 = excl;
    const float T1 = excl * q0;
    const float T2 = T1 * q1;
    const float w0 = a0 * T0;
    const float w1 = a1 * T1;
    const float w2 = a2 * T2;           // lane15: a2=0 -> w2=0

    // per-ray scalar reductions (xor-reduce leaves sum in all lanes)
    float wt   = w0 + w1 + w2;
    float dacc = w0 * 0.5f * (z0 + z1) + w1 * 0.5f * (z1 + z2) + w2 * 0.5f * (z2 + z3);
    #pragma unroll
    for (int off = 1; off < 16; off <<= 1) {
        wt   += __shfl_xor(wt,   off, 16);
        dacc += __shfl_xor(dacc, off, 16);
    }

    // weights out: lane l writes 3 consecutive (lane15 writes 2)
    float* __restrict__ w_out = out + OFF_W + (size_t)ray * SM1;
    w_out[m0]     = w0;
    w_out[m0 + 1] = w1;
    if (l < 15) w_out[m0 + 2] = w2;

    if (l == 0) {
        out[OFF_DEP + ray] = dacc / (wt + 0.001f);
        out[OFF_WT  + ray] = wt;
    }

    // ---- Phase 2: streaming color composite ------------------------------
    const float2* __restrict__ col2 =
        reinterpret_cast<const float2*>(colors) + (size_t)ray * S_SAMP * (C_CH / 2) + l;

    float2 cp = col2[0];
    float ax = 0.0f, ay = 0.0f;

    #pragma unroll
    for (int m = 0; m < SM1; ++m) {
        const float2 c = col2[(size_t)(m + 1) * (C_CH / 2)];
        const float wsrc = (m % 3 == 0) ? w0 : ((m % 3 == 1) ? w1 : w2);
        const float wv = __shfl(wsrc, m / 3, 16);   // compile-time src lane
        ax += wv * (c.x + cp.x);
        ay += wv * (c.y + cp.y);
        cp = c;
    }

    float* __restrict__ rgb = out + OFF_RGB + (size_t)ray * C_CH + 2 * l;
    rgb[0] = ax - 1.0f;
    rgb[1] = ay - 1.0f;
}

extern "C" void kernel_launch(void* const* d_in, const int* in_sizes, int n_in,
                              void* d_out, int out_size, void* d_ws, size_t ws_size,
                              hipStream_t stream) {
    const float* colors    = (const float*)d_in[0];
    const float* densities = (const float*)d_in[1];
    const float* depths    = (const float*)d_in[2];
    float* out = (float*)d_out;

    fused2_kernel<<<(NRAYS * 16) / 256, 256, 0, stream>>>(colors, densities, depths, out);
}